// Round 14
// baseline (486.973 us; speedup 1.0000x reference)
//
#include <hip/hip_runtime.h>

#define N_SEQ 16384
#define LSEQ  512
#define VOCAB 32000
#define ES    32
#define HS    64
#define LDH   72    // padded f16 stride per m-row in LDS

#define SC_RZ (-1.4426950408889634f)   // -log2(e): folded into r,z weights
#define SC_N  (-2.8853900817779268f)   // -2*log2(e): folded into n weights

typedef _Float16 v8h __attribute__((ext_vector_type(8)));
typedef float    v4f __attribute__((ext_vector_type(4)));

// ---------------- K1 (fused prep): lengths | emb->f16 | weight packs --------
#define NLB (N_SEQ / 256)          // 64 blocks: binary-search lengths
#define NEB (VOCAB * ES / 256)     // 4000 blocks: emb convert
__global__ __launch_bounds__(256) void k_prep(const int* __restrict__ x,
                                              const float* __restrict__ emb,
                                              const float* __restrict__ whh,
                                              const float* __restrict__ wih,
                                              int* __restrict__ len,
                                              int* __restrict__ hist,
                                              _Float16* __restrict__ ef,
                                              _Float16* __restrict__ wpk,
                                              _Float16* __restrict__ wpe){
  int b = blockIdx.x;
  if (b < NLB){                               // ---- lengths: binary search
    int row = b * 256 + threadIdx.x;
    const int* xr = x + (size_t)row * LSEQ;
    int lo = 0, hi = LSEQ;
    while (lo < hi){ int mid = (lo + hi) >> 1; if (xr[mid] != 0) lo = mid + 1; else hi = mid; }
    len[row] = lo;
    atomicAdd(&hist[lo], 1);
  } else if (b < NLB + NEB){                  // ---- embedding f32 -> f16
    int i = (b - NLB) * 256 + threadIdx.x;
    ef[i] = (_Float16)emb[i];
  } else if (b < NLB + NEB + 6){              // ---- pack w_hh (K=64: 2 frags)
    int tid = (b - NLB - NEB) * 256 + threadIdx.x;
    int f = tid >> 6, l = tid & 63;
    int jt = f >> 1, kf = f & 1;
    float sc = (jt < 8) ? SC_RZ : SC_N;       // exp2-arg scale folded in
    #pragma unroll
    for (int i = 0; i < 8; ++i){
      int row = jt * 16 + (l & 15);
      int col = kf * 32 + (l >> 4) * 8 + i;
      wpk[(size_t)tid * 8 + i] = (_Float16)(sc * whh[row * HS + col]);
    }
  } else {                                    // ---- pack w_ih (K=32: 1 frag)
    int tid = (b - NLB - NEB - 6) * 256 + threadIdx.x;
    int tile = tid >> 6, l = tid & 63;
    float sc = ((tile >> 2) < 2) ? SC_RZ : SC_N;
    #pragma unroll
    for (int i = 0; i < 8; ++i){
      int row = tile * 16 + (l & 15);
      int col = (l >> 4) * 8 + i;
      wpe[(size_t)tid * 8 + i] = (_Float16)(sc * wih[row * ES + col]);
    }
  }
}

// ---------------- K2: fused scan + scatter ----------------------------------
__global__ __launch_bounds__(1024) void k_scatter(const int* __restrict__ hist,
                                                  const int* __restrict__ len,
                                                  int* __restrict__ gcnt,
                                                  int* __restrict__ perm){
  __shared__ int buf[1024];
  __shared__ int offs[513];
  int i = threadIdx.x;
  buf[i] = (i < 513) ? hist[i] : 0;
  __syncthreads();
  for (int d = 1; d < 1024; d <<= 1){
    int v = (i >= d) ? buf[i - d] : 0;
    __syncthreads();
    buf[i] += v;
    __syncthreads();
  }
  if (i < 513) offs[i] = (i == 0) ? 0 : buf[i - 1];
  __syncthreads();
  int s = blockIdx.x * 1024 + i;
  int l = len[s];
  int pos = offs[l] + atomicAdd(&gcnt[l], 1);
  perm[pos] = s;
}

// ---------------- K3: recurrence -------------------------------------------
// R13 structure with the schedule changed from equal-SUM (serpentine) to
// LIKE-LENGTH CU grouping: rank = (blockIdx%256)*4 + blockIdx/256, so the 4
// blocks sharing a CU (blockIdx = k+256m, round-robin dispatch — model
// validated by R7's serpentine win) get ADJACENT sorted groups with nearly
// identical tmax. All 4 chains/SIMD stay live for the CU's whole run — no
// endgame where the 512-step block runs solo at chain-latency T (the 34% gap
// between measured T=1195 and the 790-cyc VALU floor). Worst case (dispatch
// model wrong) degrades to the old mixed-length behavior, not below.
// Token LDS layout is now t-major (tok[t*16+s]): in-loop reads are 32 B
// contiguous + quad-broadcast = conflict-free (was 4-way at stride 1024 B).
__global__ __launch_bounds__(256, 4) void k_gru(
    const int* __restrict__ x, const _Float16* __restrict__ ef,
    const _Float16* __restrict__ wpk, const _Float16* __restrict__ wpe,
    const float* __restrict__ bih, const float* __restrict__ bhh,
    const int* __restrict__ perm, const int* __restrict__ len,
    float* __restrict__ out)
{
  __shared__ __align__(16) _Float16 hb[2][16 * LDH];
  __shared__ unsigned short tok[LSEQ * 16];   // 16 KB staged tokens, t-major
  int qt   = threadIdx.x >> 6;
  int rank = (int)(blockIdx.x & 255) * 4 + (int)(blockIdx.x >> 8); // 0 = longest
  int grp  = 1023 - rank;                             // ascending-sorted index
  int lane = threadIdx.x & 63;
  int q = lane >> 4, c = lane & 15;
  int uu = qt*16 + c;

  v8h bfh[3][2], bfe[3];
  #pragma unroll
  for (int g = 0; g < 3; ++g){
    int tile = g*4 + qt;
    #pragma unroll
    for (int kf = 0; kf < 2; ++kf)
      bfh[g][kf] = *(const v8h*)(wpk + ((size_t)(tile*2 + kf)*64 + lane)*8);
    bfe[g] = *(const v8h*)(wpe + ((size_t)tile*64 + lane)*8);
  }

  int sq[4], ln[4];
  #pragma unroll
  for (int r = 0; r < 4; ++r){
    int s = perm[grp * 16 + q*4 + r];
    sq[r] = s;
    ln[r] = len[s];
  }
  float br  = SC_RZ * (bih[uu]      + bhh[uu]);
  float bz  = SC_RZ * (bih[HS + uu] + bhh[HS + uu]);
  float ben = SC_N  *  bih[2*HS + uu];
  float bhn = SC_N  *  bhh[2*HS + uu];
  v4f brq  = {br, br, br, br};
  v4f bzq  = {bz, bz, bz, bz};
  v4f benq = {ben, ben, ben, ben};
  v4f bhnq = {bhn, bhn, bhn, bhn};

  float h[4];
  #pragma unroll
  for (int r = 0; r < 4; ++r) h[r] = 0.f;

  for (int i = threadIdx.x; i < 16*LDH; i += 256) hb[0][i] = (_Float16)0.f;

  // stage tokens t-major: consecutive tid -> consecutive t of one seq
  // (coalesced global read); LDS write conflicts are one-time trivia.
  for (int j = threadIdx.x; j < 16*LSEQ; j += 256){
    int s = j >> 9, tt = j & (LSEQ-1);
    tok[tt*16 + s] = (unsigned short)x[(size_t)perm[grp*16 + s] * LSEQ + tt];
  }
  __syncthreads();

  int tmax = max(max(ln[0], ln[1]), max(ln[2], ln[3]));
  tmax = max(tmax, __shfl_xor(tmax, 16, 64));
  tmax = max(tmax, __shfl_xor(tmax, 32, 64));
  int tmin = min(min(ln[0], ln[1]), min(ln[2], ln[3]));
  tmin = min(tmin, __shfl_xor(tmin, 16, 64));
  tmin = min(tmin, __shfl_xor(tmin, 32, 64));

  v8h aec, aen;                       // emb frags: consume one, load the other
  v4f pra, prb, pza, pzb, dea, deb;   // e-partials: r, z, n (ping/pong)
  {
    int tk0 = tok[0*16 + c];
    aec = *(const v8h*)(ef + (size_t)tk0 * ES + q*8);
    pra = __builtin_amdgcn_mfma_f32_16x16x32_f16(aec, bfe[0], brq,  0,0,0);
    pza = __builtin_amdgcn_mfma_f32_16x16x32_f16(aec, bfe[1], bzq,  0,0,0);
    dea = __builtin_amdgcn_mfma_f32_16x16x32_f16(aec, bfe[2], benq, 0,0,0);
    int tk1 = tok[1*16 + c];
    aen = *(const v8h*)(ef + (size_t)tk1 * ES + q*8);   // emb for t=1
  }

  // ACONS = emb(t+1), loaded one full step ago (no vmcnt stall at its use);
  // ALOAD <- emb(t+2) issued this step (token from LDS, instant).
  #define GRU_STEP(FREEZE, ACONS, ALOAD, PRR, PRZ, DEN, PRRn, PRZn, DENn, RB, WB) \
  {                                                                            \
    int tkn = tok[((t + 2) & (LSEQ-1))*16 + c];                                \
    v8h a0 = *(const v8h*)(&hb[RB][c*LDH + q*8]);                              \
    v8h a1 = *(const v8h*)(&hb[RB][c*LDH + 32 + q*8]);                         \
    v4f zr  = __builtin_amdgcn_mfma_f32_16x16x32_f16(a1, bfh[0][1], PRR, 0,0,0);\
    v4f Dr  = __builtin_amdgcn_mfma_f32_16x16x32_f16(a0, bfh[0][0], zr,  0,0,0);\
    v4f zz  = __builtin_amdgcn_mfma_f32_16x16x32_f16(a1, bfh[1][1], PRZ, 0,0,0);\
    v4f Dz  = __builtin_amdgcn_mfma_f32_16x16x32_f16(a0, bfh[1][0], zz,  0,0,0);\
    v4f zh  = __builtin_amdgcn_mfma_f32_16x16x32_f16(a1, bfh[2][1], bhnq,0,0,0);\
    v4f Dhn = __builtin_amdgcn_mfma_f32_16x16x32_f16(a0, bfh[2][0], zh,  0,0,0);\
    _Pragma("unroll")                                                          \
    for (int r = 0; r < 4; ++r){                                               \
      float rg   = __builtin_amdgcn_rcpf(1.f + __builtin_amdgcn_exp2f(Dr[r])); \
      float zg   = __builtin_amdgcn_rcpf(1.f + __builtin_amdgcn_exp2f(Dz[r])); \
      float te   = __builtin_amdgcn_exp2f(DEN[r] + rg * Dhn[r]);               \
      float ng   = fmaf(2.f, __builtin_amdgcn_rcpf(1.f + te), -1.f);           \
      float hnew = ng + zg * (h[r] - ng);                                      \
      h[r]       = (FREEZE && t >= ln[r]) ? h[r] : hnew;                       \
    }                                                                          \
    PRRn = __builtin_amdgcn_mfma_f32_16x16x32_f16(ACONS, bfe[0], brq,  0,0,0); \
    PRZn = __builtin_amdgcn_mfma_f32_16x16x32_f16(ACONS, bfe[1], bzq,  0,0,0); \
    DENn = __builtin_amdgcn_mfma_f32_16x16x32_f16(ACONS, bfe[2], benq, 0,0,0); \
    ALOAD = *(const v8h*)(ef + (size_t)tkn * ES + q*8);  /* emb t+2 */         \
    _Pragma("unroll")                                                          \
    for (int r = 0; r < 4; ++r)                                                \
      hb[WB][(q*4 + r)*LDH + uu] = (_Float16)h[r];                             \
    __syncthreads();                                                           \
  }

  int t = 0;
  for (; t + 1 < tmin; ){   // no-freeze main loop (t and t+1 both < all ln)
    GRU_STEP(0, aen, aec, pra, pza, dea, prb, pzb, deb, 0, 1); ++t;
    GRU_STEP(0, aec, aen, prb, pzb, deb, pra, pza, dea, 1, 0); ++t;
  }
  for (; t + 1 < tmax; ){   // tail pairs with freeze (parity preserved)
    GRU_STEP(1, aen, aec, pra, pza, dea, prb, pzb, deb, 0, 1); ++t;
    GRU_STEP(1, aec, aen, prb, pzb, deb, pra, pza, dea, 1, 0); ++t;
  }
  if (t < tmax){
    GRU_STEP(1, aen, aec, pra, pza, dea, prb, pzb, deb, 0, 1); ++t;
  }
  #undef GRU_STEP

  #pragma unroll
  for (int r = 0; r < 4; ++r)
    out[(size_t)sq[r] * HS + uu] = h[r];
}

extern "C" void kernel_launch(void* const* d_in, const int* in_sizes, int n_in,
                              void* d_out, int out_size, void* d_ws, size_t ws_size,
                              hipStream_t stream){
  const int*   x   = (const int*)  d_in[0];
  const float* emb = (const float*)d_in[1];
  const float* wih = (const float*)d_in[2];
  const float* whh = (const float*)d_in[3];
  const float* bih = (const float*)d_in[4];
  const float* bhh = (const float*)d_in[5];
  float* out = (float*)d_out;

  char* ws = (char*)d_ws;
  size_t off = 0;
  _Float16* ef  = (_Float16*)(ws + off);  off += (size_t)VOCAB * ES * sizeof(_Float16);
  _Float16* wpk = (_Float16*)(ws + off);  off += (size_t)24 * 64 * 8 * sizeof(_Float16);
  _Float16* wpe = (_Float16*)(ws + off);  off += (size_t)12 * 64 * 8 * sizeof(_Float16);
  off = (off + 255) & ~(size_t)255;
  int* len  = (int*)(ws + off);           off += (size_t)N_SEQ * sizeof(int);
  int* perm = (int*)(ws + off);           off += (size_t)N_SEQ * sizeof(int);
  int* hist = (int*)(ws + off);           off += 513 * sizeof(int);
  int* gcnt = (int*)(ws + off);           off += 513 * sizeof(int);

  hipMemsetAsync(hist, 0, 2 * 513 * sizeof(int), stream);   // hist + gcnt
  k_prep   <<<NLB + NEB + 9, 256, 0, stream>>>(x, emb, whh, wih, len, hist, ef, wpk, wpe);
  k_scatter<<<N_SEQ / 1024, 1024, 0, stream>>>(hist, len, gcnt, perm);
  k_gru    <<<N_SEQ / 16,    256, 0, stream>>>(x, ef, wpk, wpe, bih, bhh, perm, len, out);
}

// Round 15
// 315.336 us; speedup vs baseline: 1.5443x; 1.5443x over previous
//
#include <hip/hip_runtime.h>

#define N_SEQ 16384
#define LSEQ  512
#define VOCAB 32000
#define ES    32
#define HS    64
#define LDH   72    // padded f16 stride per m-row in LDS

#define SC_RZ (-1.4426950408889634f)   // -log2(e): folded into r,z weights
#define SC_N  (-2.8853900817779268f)   // -2*log2(e): folded into n weights

typedef _Float16 v8h __attribute__((ext_vector_type(8)));
typedef _Float16 v4h __attribute__((ext_vector_type(4)));
typedef float    v4f __attribute__((ext_vector_type(4)));

// ---------------- K1: lengths only (fast — unblocks the scatter ASAP) -------
__global__ __launch_bounds__(256) void k_len(const int* __restrict__ x,
                                             int* __restrict__ len,
                                             int* __restrict__ hist){
  int row = blockIdx.x * 256 + threadIdx.x;
  const int* xr = x + (size_t)row * LSEQ;
  int lo = 0, hi = LSEQ;                     // prefix property: x[t]!=0 iff t<len
  while (lo < hi){ int mid = (lo + hi) >> 1; if (xr[mid] != 0) lo = mid + 1; else hi = mid; }
  len[row] = lo;
  atomicAdd(&hist[lo], 1);
}

// ---------------- K2 (fused): scatter | emb->f16 (x4) | weight packs --------
// b<16: scan+scatter; b<272: emb float4 convert; b=272,273: whh; b=274: wih.
__global__ __launch_bounds__(1024) void k_mid(const int* __restrict__ hist,
                                              const int* __restrict__ len,
                                              int* __restrict__ gcnt,
                                              int* __restrict__ perm,
                                              const float* __restrict__ emb,
                                              _Float16* __restrict__ ef,
                                              const float* __restrict__ whh,
                                              _Float16* __restrict__ wpk,
                                              const float* __restrict__ wih,
                                              _Float16* __restrict__ wpe){
  int b = blockIdx.x;
  if (b < 16){                                // ---- redundant scan + scatter
    __shared__ int buf[1024];
    __shared__ int offs[513];
    int i = threadIdx.x;
    buf[i] = (i < 513) ? hist[i] : 0;
    __syncthreads();
    for (int d = 1; d < 1024; d <<= 1){
      int v = (i >= d) ? buf[i - d] : 0;
      __syncthreads();
      buf[i] += v;
      __syncthreads();
    }
    if (i < 513) offs[i] = (i == 0) ? 0 : buf[i - 1];
    __syncthreads();
    int s = b * 1024 + i;
    int l = len[s];
    int pos = offs[l] + atomicAdd(&gcnt[l], 1);
    perm[pos] = s;
  } else if (b < 272){                        // ---- embedding f32 -> f16, x4
    int idx = (b - 16) * 1024 + threadIdx.x;  // vec4 index
    if (idx < VOCAB * ES / 4){
      float4 v = ((const float4*)emb)[idx];
      v4h o = {(_Float16)v.x, (_Float16)v.y, (_Float16)v.z, (_Float16)v.w};
      ((v4h*)ef)[idx] = o;
    }
  } else if (b < 274){                        // ---- pack w_hh (K=64: 2 frags)
    int tid = (b - 272) * 1024 + threadIdx.x;
    if (tid < 24 * 64){
      int f = tid >> 6, l = tid & 63;
      int jt = f >> 1, kf = f & 1;
      float sc = (jt < 8) ? SC_RZ : SC_N;
      #pragma unroll
      for (int i = 0; i < 8; ++i){
        int row = jt * 16 + (l & 15);
        int col = kf * 32 + (l >> 4) * 8 + i;
        wpk[(size_t)tid * 8 + i] = (_Float16)(sc * whh[row * HS + col]);
      }
    }
  } else {                                    // ---- pack w_ih (K=32: 1 frag)
    int tid = threadIdx.x;
    if (tid < 12 * 64){
      int tile = tid >> 6, l = tid & 63;
      float sc = ((tile >> 2) < 2) ? SC_RZ : SC_N;
      #pragma unroll
      for (int i = 0; i < 8; ++i){
        int row = tile * 16 + (l & 15);
        int col = (l >> 4) * 8 + i;
        wpe[(size_t)tid * 8 + i] = (_Float16)(sc * wih[row * ES + col]);
      }
    }
  }
}

// ---------------- K3: recurrence -------------------------------------------
// Consolidated best-of-rounds: serpentine schedule (R13 — equal per-CU totals,
// the measured optimum of {serpentine-4: 624K cyc, dual/chained-2: 780K,
// like-length-4: 1044K}), t-major token LDS layout (R14 — conflict-free
// in-loop reads: 32B contiguous + quad broadcast), 4-way u-split, distance-2
// emb prefetch, folded exp2 scales, select-free main loop.
__global__ __launch_bounds__(256, 4) void k_gru(
    const int* __restrict__ x, const _Float16* __restrict__ ef,
    const _Float16* __restrict__ wpk, const _Float16* __restrict__ wpe,
    const float* __restrict__ bih, const float* __restrict__ bhh,
    const int* __restrict__ perm, const int* __restrict__ len,
    float* __restrict__ out)
{
  __shared__ __align__(16) _Float16 hb[2][16 * LDH];
  __shared__ unsigned short tok[LSEQ * 16];   // 16 KB staged tokens, t-major
  int qt   = threadIdx.x >> 6;
  int w = blockIdx.x >> 8, cq = blockIdx.x & 255;
  int rank = w * 256 + ((w & 1) ? (255 - cq) : cq);   // 0 = longest
  int grp  = 1023 - rank;                             // ascending-sorted index
  int lane = threadIdx.x & 63;
  int q = lane >> 4, c = lane & 15;
  int uu = qt*16 + c;

  v8h bfh[3][2], bfe[3];
  #pragma unroll
  for (int g = 0; g < 3; ++g){
    int tile = g*4 + qt;
    #pragma unroll
    for (int kf = 0; kf < 2; ++kf)
      bfh[g][kf] = *(const v8h*)(wpk + ((size_t)(tile*2 + kf)*64 + lane)*8);
    bfe[g] = *(const v8h*)(wpe + ((size_t)tile*64 + lane)*8);
  }

  int sq[4], ln[4];
  #pragma unroll
  for (int r = 0; r < 4; ++r){
    int s = perm[grp * 16 + q*4 + r];
    sq[r] = s;
    ln[r] = len[s];
  }
  float br  = SC_RZ * (bih[uu]      + bhh[uu]);
  float bz  = SC_RZ * (bih[HS + uu] + bhh[HS + uu]);
  float ben = SC_N  *  bih[2*HS + uu];
  float bhn = SC_N  *  bhh[2*HS + uu];
  v4f brq  = {br, br, br, br};
  v4f bzq  = {bz, bz, bz, bz};
  v4f benq = {ben, ben, ben, ben};
  v4f bhnq = {bhn, bhn, bhn, bhn};

  float h[4];
  #pragma unroll
  for (int r = 0; r < 4; ++r) h[r] = 0.f;

  for (int i = threadIdx.x; i < 16*LDH; i += 256) hb[0][i] = (_Float16)0.f;

  // stage tokens t-major: consecutive tid -> consecutive t of one seq
  // (coalesced global read); in-loop reads conflict-free.
  for (int j = threadIdx.x; j < 16*LSEQ; j += 256){
    int s = j >> 9, tt = j & (LSEQ-1);
    tok[tt*16 + s] = (unsigned short)x[(size_t)perm[grp*16 + s] * LSEQ + tt];
  }
  __syncthreads();

  int tmax = max(max(ln[0], ln[1]), max(ln[2], ln[3]));
  tmax = max(tmax, __shfl_xor(tmax, 16, 64));
  tmax = max(tmax, __shfl_xor(tmax, 32, 64));
  int tmin = min(min(ln[0], ln[1]), min(ln[2], ln[3]));
  tmin = min(tmin, __shfl_xor(tmin, 16, 64));
  tmin = min(tmin, __shfl_xor(tmin, 32, 64));

  v8h aec, aen;                       // emb frags: consume one, load the other
  v4f pra, prb, pza, pzb, dea, deb;   // e-partials: r, z, n (ping/pong)
  {
    int tk0 = tok[0*16 + c];
    aec = *(const v8h*)(ef + (size_t)tk0 * ES + q*8);
    pra = __builtin_amdgcn_mfma_f32_16x16x32_f16(aec, bfe[0], brq,  0,0,0);
    pza = __builtin_amdgcn_mfma_f32_16x16x32_f16(aec, bfe[1], bzq,  0,0,0);
    dea = __builtin_amdgcn_mfma_f32_16x16x32_f16(aec, bfe[2], benq, 0,0,0);
    int tk1 = tok[1*16 + c];
    aen = *(const v8h*)(ef + (size_t)tk1 * ES + q*8);   // emb for t=1
  }

  // ACONS = emb(t+1), loaded one full step ago (no vmcnt stall at its use);
  // ALOAD <- emb(t+2) issued this step (token from LDS, instant).
  #define GRU_STEP(FREEZE, ACONS, ALOAD, PRR, PRZ, DEN, PRRn, PRZn, DENn, RB, WB) \
  {                                                                            \
    int tkn = tok[((t + 2) & (LSEQ-1))*16 + c];                                \
    v8h a0 = *(const v8h*)(&hb[RB][c*LDH + q*8]);                              \
    v8h a1 = *(const v8h*)(&hb[RB][c*LDH + 32 + q*8]);                         \
    v4f zr  = __builtin_amdgcn_mfma_f32_16x16x32_f16(a1, bfh[0][1], PRR, 0,0,0);\
    v4f Dr  = __builtin_amdgcn_mfma_f32_16x16x32_f16(a0, bfh[0][0], zr,  0,0,0);\
    v4f zz  = __builtin_amdgcn_mfma_f32_16x16x32_f16(a1, bfh[1][1], PRZ, 0,0,0);\
    v4f Dz  = __builtin_amdgcn_mfma_f32_16x16x32_f16(a0, bfh[1][0], zz,  0,0,0);\
    v4f zh  = __builtin_amdgcn_mfma_f32_16x16x32_f16(a1, bfh[2][1], bhnq,0,0,0);\
    v4f Dhn = __builtin_amdgcn_mfma_f32_16x16x32_f16(a0, bfh[2][0], zh,  0,0,0);\
    _Pragma("unroll")                                                          \
    for (int r = 0; r < 4; ++r){                                               \
      float rg   = __builtin_amdgcn_rcpf(1.f + __builtin_amdgcn_exp2f(Dr[r])); \
      float zg   = __builtin_amdgcn_rcpf(1.f + __builtin_amdgcn_exp2f(Dz[r])); \
      float te   = __builtin_amdgcn_exp2f(DEN[r] + rg * Dhn[r]);               \
      float ng   = fmaf(2.f, __builtin_amdgcn_rcpf(1.f + te), -1.f);           \
      float hnew = ng + zg * (h[r] - ng);                                      \
      h[r]       = (FREEZE && t >= ln[r]) ? h[r] : hnew;                       \
    }                                                                          \
    PRRn = __builtin_amdgcn_mfma_f32_16x16x32_f16(ACONS, bfe[0], brq,  0,0,0); \
    PRZn = __builtin_amdgcn_mfma_f32_16x16x32_f16(ACONS, bfe[1], bzq,  0,0,0); \
    DENn = __builtin_amdgcn_mfma_f32_16x16x32_f16(ACONS, bfe[2], benq, 0,0,0); \
    ALOAD = *(const v8h*)(ef + (size_t)tkn * ES + q*8);  /* emb t+2 */         \
    _Pragma("unroll")                                                          \
    for (int r = 0; r < 4; ++r)                                                \
      hb[WB][(q*4 + r)*LDH + uu] = (_Float16)h[r];                             \
    __syncthreads();                                                           \
  }

  int t = 0;
  for (; t + 1 < tmin; ){   // no-freeze main loop (t and t+1 both < all ln)
    GRU_STEP(0, aen, aec, pra, pza, dea, prb, pzb, deb, 0, 1); ++t;
    GRU_STEP(0, aec, aen, prb, pzb, deb, pra, pza, dea, 1, 0); ++t;
  }
  for (; t + 1 < tmax; ){   // tail pairs with freeze (parity preserved)
    GRU_STEP(1, aen, aec, pra, pza, dea, prb, pzb, deb, 0, 1); ++t;
    GRU_STEP(1, aec, aen, prb, pzb, deb, pra, pza, dea, 1, 0); ++t;
  }
  if (t < tmax){
    GRU_STEP(1, aen, aec, pra, pza, dea, prb, pzb, deb, 0, 1); ++t;
  }
  #undef GRU_STEP

  #pragma unroll
  for (int r = 0; r < 4; ++r)
    out[(size_t)sq[r] * HS + uu] = h[r];
}

extern "C" void kernel_launch(void* const* d_in, const int* in_sizes, int n_in,
                              void* d_out, int out_size, void* d_ws, size_t ws_size,
                              hipStream_t stream){
  const int*   x   = (const int*)  d_in[0];
  const float* emb = (const float*)d_in[1];
  const float* wih = (const float*)d_in[2];
  const float* whh = (const float*)d_in[3];
  const float* bih = (const float*)d_in[4];
  const float* bhh = (const float*)d_in[5];
  float* out = (float*)d_out;

  char* ws = (char*)d_ws;
  size_t off = 0;
  _Float16* ef  = (_Float16*)(ws + off);  off += (size_t)VOCAB * ES * sizeof(_Float16);
  _Float16* wpk = (_Float16*)(ws + off);  off += (size_t)24 * 64 * 8 * sizeof(_Float16);
  _Float16* wpe = (_Float16*)(ws + off);  off += (size_t)12 * 64 * 8 * sizeof(_Float16);
  off = (off + 255) & ~(size_t)255;
  int* len  = (int*)(ws + off);           off += (size_t)N_SEQ * sizeof(int);
  int* perm = (int*)(ws + off);           off += (size_t)N_SEQ * sizeof(int);
  int* hist = (int*)(ws + off);           off += 513 * sizeof(int);
  int* gcnt = (int*)(ws + off);           off += 513 * sizeof(int);

  hipMemsetAsync(hist, 0, 2 * 513 * sizeof(int), stream);   // hist + gcnt
  k_len <<<N_SEQ / 256, 256,  0, stream>>>(x, len, hist);
  k_mid <<<275,         1024, 0, stream>>>(hist, len, gcnt, perm,
                                           emb, ef, whh, wpk, wih, wpe);
  k_gru <<<N_SEQ / 16,  256,  0, stream>>>(x, ef, wpk, wpe, bih, bhh, perm, len, out);
}

// Round 17
// 311.873 us; speedup vs baseline: 1.5614x; 1.0111x over previous
//
#include <hip/hip_runtime.h>

#define N_SEQ 16384
#define LSEQ  512
#define VOCAB 32000
#define ES    32
#define HS    64
#define LDH   72    // padded f16 stride per m-row in LDS

#define SC_RZ (-1.4426950408889634f)   // -log2(e): folded into r,z weights
#define SC_N  (-2.8853900817779268f)   // -2*log2(e): folded into n weights

typedef _Float16 v8h __attribute__((ext_vector_type(8)));
typedef _Float16 v4h __attribute__((ext_vector_type(4)));
typedef float    v4f __attribute__((ext_vector_type(4)));

// ---------------- K1 (fused prep, all-parallel): lengths | emb x4 | packs ---
// Grid = NLB + NEB + 9: 64 len + 1000 emb + 6 whh-pack + 3 wih-pack blocks.
// (R16 bug: grid was +7 -> only 1 of 3 wih blocks ran; wpe[256..767] stayed
// poisoned and the e-side matmul used garbage. This is R13's proven layout.)
#define NLB (N_SEQ / 256)              // 64 blocks: binary-search lengths
#define NEB (VOCAB * ES / 4 / 256)     // 1000 blocks: emb float4 convert
__global__ __launch_bounds__(256) void k_prep(const int* __restrict__ x,
                                              const float* __restrict__ emb,
                                              const float* __restrict__ whh,
                                              const float* __restrict__ wih,
                                              int* __restrict__ len,
                                              int* __restrict__ hist,
                                              _Float16* __restrict__ ef,
                                              _Float16* __restrict__ wpk,
                                              _Float16* __restrict__ wpe){
  int b = blockIdx.x;
  if (b < NLB){                               // ---- lengths: binary search
    int row = b * 256 + threadIdx.x;          // prefix property: x[t]!=0 iff t<len
    const int* xr = x + (size_t)row * LSEQ;
    int lo = 0, hi = LSEQ;
    while (lo < hi){ int mid = (lo + hi) >> 1; if (xr[mid] != 0) lo = mid + 1; else hi = mid; }
    len[row] = lo;
    atomicAdd(&hist[lo], 1);
  } else if (b < NLB + NEB){                  // ---- embedding f32 -> f16, x4
    int idx = (b - NLB) * 256 + threadIdx.x;  // vec4 index
    float4 v = ((const float4*)emb)[idx];
    v4h o = {(_Float16)v.x, (_Float16)v.y, (_Float16)v.z, (_Float16)v.w};
    ((v4h*)ef)[idx] = o;
  } else if (b < NLB + NEB + 6){              // ---- pack w_hh (K=64: 2 frags)
    int tid = (b - NLB - NEB) * 256 + threadIdx.x;   // 6*256 = 1536 = 24*64
    int f = tid >> 6, l = tid & 63;
    int jt = f >> 1, kf = f & 1;
    float sc = (jt < 8) ? SC_RZ : SC_N;       // exp2-arg scale folded in
    #pragma unroll
    for (int i = 0; i < 8; ++i){
      int row = jt * 16 + (l & 15);
      int col = kf * 32 + (l >> 4) * 8 + i;
      wpk[(size_t)tid * 8 + i] = (_Float16)(sc * whh[row * HS + col]);
    }
  } else {                                    // ---- pack w_ih (K=32: 1 frag)
    int tid = (b - NLB - NEB - 6) * 256 + threadIdx.x;  // 3*256 = 768 = 12*64
    int tile = tid >> 6, l = tid & 63;
    float sc = ((tile >> 2) < 2) ? SC_RZ : SC_N;
    #pragma unroll
    for (int i = 0; i < 8; ++i){
      int row = tile * 16 + (l & 15);
      int col = (l >> 4) * 8 + i;
      wpe[(size_t)tid * 8 + i] = (_Float16)(sc * wih[row * ES + col]);
    }
  }
}

// ---------------- K2: fused scan + scatter ----------------------------------
// 16 blocks x 1024: each block redundantly scans hist[0..512] in LDS, then
// scatters its 1024 seq ids via global per-bucket atomic counters.
__global__ __launch_bounds__(1024) void k_scatter(const int* __restrict__ hist,
                                                  const int* __restrict__ len,
                                                  int* __restrict__ gcnt,
                                                  int* __restrict__ perm){
  __shared__ int buf[1024];
  __shared__ int offs[513];
  int i = threadIdx.x;
  buf[i] = (i < 513) ? hist[i] : 0;
  __syncthreads();
  for (int d = 1; d < 1024; d <<= 1){
    int v = (i >= d) ? buf[i - d] : 0;
    __syncthreads();
    buf[i] += v;
    __syncthreads();
  }
  if (i < 513) offs[i] = (i == 0) ? 0 : buf[i - 1];
  __syncthreads();
  int s = blockIdx.x * 1024 + i;
  int l = len[s];
  int pos = offs[l] + atomicAdd(&gcnt[l], 1);
  perm[pos] = s;
}

// ---------------- K3: recurrence (R15 — best measured, unchanged) -----------
// Serpentine schedule (equal per-CU totals; measured optimum of all schedule
// families tried), 4-way u-split, t-major conflict-free token LDS, distance-2
// emb prefetch, folded exp2 scales, select-free main loop.
__global__ __launch_bounds__(256, 4) void k_gru(
    const int* __restrict__ x, const _Float16* __restrict__ ef,
    const _Float16* __restrict__ wpk, const _Float16* __restrict__ wpe,
    const float* __restrict__ bih, const float* __restrict__ bhh,
    const int* __restrict__ perm, const int* __restrict__ len,
    float* __restrict__ out)
{
  __shared__ __align__(16) _Float16 hb[2][16 * LDH];
  __shared__ unsigned short tok[LSEQ * 16];   // 16 KB staged tokens, t-major
  int qt   = threadIdx.x >> 6;
  int w = blockIdx.x >> 8, cq = blockIdx.x & 255;
  int rank = w * 256 + ((w & 1) ? (255 - cq) : cq);   // 0 = longest
  int grp  = 1023 - rank;                             // ascending-sorted index
  int lane = threadIdx.x & 63;
  int q = lane >> 4, c = lane & 15;
  int uu = qt*16 + c;

  v8h bfh[3][2], bfe[3];
  #pragma unroll
  for (int g = 0; g < 3; ++g){
    int tile = g*4 + qt;
    #pragma unroll
    for (int kf = 0; kf < 2; ++kf)
      bfh[g][kf] = *(const v8h*)(wpk + ((size_t)(tile*2 + kf)*64 + lane)*8);
    bfe[g] = *(const v8h*)(wpe + ((size_t)tile*64 + lane)*8);
  }

  int sq[4], ln[4];
  #pragma unroll
  for (int r = 0; r < 4; ++r){
    int s = perm[grp * 16 + q*4 + r];
    sq[r] = s;
    ln[r] = len[s];
  }
  float br  = SC_RZ * (bih[uu]      + bhh[uu]);
  float bz  = SC_RZ * (bih[HS + uu] + bhh[HS + uu]);
  float ben = SC_N  *  bih[2*HS + uu];
  float bhn = SC_N  *  bhh[2*HS + uu];
  v4f brq  = {br, br, br, br};
  v4f bzq  = {bz, bz, bz, bz};
  v4f benq = {ben, ben, ben, ben};
  v4f bhnq = {bhn, bhn, bhn, bhn};

  float h[4];
  #pragma unroll
  for (int r = 0; r < 4; ++r) h[r] = 0.f;

  for (int i = threadIdx.x; i < 16*LDH; i += 256) hb[0][i] = (_Float16)0.f;

  // stage tokens t-major: consecutive tid -> consecutive t of one seq
  // (coalesced global read); in-loop reads conflict-free (32B + broadcast).
  for (int j = threadIdx.x; j < 16*LSEQ; j += 256){
    int s = j >> 9, tt = j & (LSEQ-1);
    tok[tt*16 + s] = (unsigned short)x[(size_t)perm[grp*16 + s] * LSEQ + tt];
  }
  __syncthreads();

  int tmax = max(max(ln[0], ln[1]), max(ln[2], ln[3]));
  tmax = max(tmax, __shfl_xor(tmax, 16, 64));
  tmax = max(tmax, __shfl_xor(tmax, 32, 64));
  int tmin = min(min(ln[0], ln[1]), min(ln[2], ln[3]));
  tmin = min(tmin, __shfl_xor(tmin, 16, 64));
  tmin = min(tmin, __shfl_xor(tmin, 32, 64));

  v8h aec, aen;                       // emb frags: consume one, load the other
  v4f pra, prb, pza, pzb, dea, deb;   // e-partials: r, z, n (ping/pong)
  {
    int tk0 = tok[0*16 + c];
    aec = *(const v8h*)(ef + (size_t)tk0 * ES + q*8);
    pra = __builtin_amdgcn_mfma_f32_16x16x32_f16(aec, bfe[0], brq,  0,0,0);
    pza = __builtin_amdgcn_mfma_f32_16x16x32_f16(aec, bfe[1], bzq,  0,0,0);
    dea = __builtin_amdgcn_mfma_f32_16x16x32_f16(aec, bfe[2], benq, 0,0,0);
    int tk1 = tok[1*16 + c];
    aen = *(const v8h*)(ef + (size_t)tk1 * ES + q*8);   // emb for t=1
  }

  // ACONS = emb(t+1), loaded one full step ago (no vmcnt stall at its use);
  // ALOAD <- emb(t+2) issued this step (token from LDS, instant).
  #define GRU_STEP(FREEZE, ACONS, ALOAD, PRR, PRZ, DEN, PRRn, PRZn, DENn, RB, WB) \
  {                                                                            \
    int tkn = tok[((t + 2) & (LSEQ-1))*16 + c];                                \
    v8h a0 = *(const v8h*)(&hb[RB][c*LDH + q*8]);                              \
    v8h a1 = *(const v8h*)(&hb[RB][c*LDH + 32 + q*8]);                         \
    v4f zr  = __builtin_amdgcn_mfma_f32_16x16x32_f16(a1, bfh[0][1], PRR, 0,0,0);\
    v4f Dr  = __builtin_amdgcn_mfma_f32_16x16x32_f16(a0, bfh[0][0], zr,  0,0,0);\
    v4f zz  = __builtin_amdgcn_mfma_f32_16x16x32_f16(a1, bfh[1][1], PRZ, 0,0,0);\
    v4f Dz  = __builtin_amdgcn_mfma_f32_16x16x32_f16(a0, bfh[1][0], zz,  0,0,0);\
    v4f zh  = __builtin_amdgcn_mfma_f32_16x16x32_f16(a1, bfh[2][1], bhnq,0,0,0);\
    v4f Dhn = __builtin_amdgcn_mfma_f32_16x16x32_f16(a0, bfh[2][0], zh,  0,0,0);\
    _Pragma("unroll")                                                          \
    for (int r = 0; r < 4; ++r){                                               \
      float rg   = __builtin_amdgcn_rcpf(1.f + __builtin_amdgcn_exp2f(Dr[r])); \
      float zg   = __builtin_amdgcn_rcpf(1.f + __builtin_amdgcn_exp2f(Dz[r])); \
      float te   = __builtin_amdgcn_exp2f(DEN[r] + rg * Dhn[r]);               \
      float ng   = fmaf(2.f, __builtin_amdgcn_rcpf(1.f + te), -1.f);           \
      float hnew = ng + zg * (h[r] - ng);                                      \
      h[r]       = (FREEZE && t >= ln[r]) ? h[r] : hnew;                       \
    }                                                                          \
    PRRn = __builtin_amdgcn_mfma_f32_16x16x32_f16(ACONS, bfe[0], brq,  0,0,0); \
    PRZn = __builtin_amdgcn_mfma_f32_16x16x32_f16(ACONS, bfe[1], bzq,  0,0,0); \
    DENn = __builtin_amdgcn_mfma_f32_16x16x32_f16(ACONS, bfe[2], benq, 0,0,0); \
    ALOAD = *(const v8h*)(ef + (size_t)tkn * ES + q*8);  /* emb t+2 */         \
    _Pragma("unroll")                                                          \
    for (int r = 0; r < 4; ++r)                                                \
      hb[WB][(q*4 + r)*LDH + uu] = (_Float16)h[r];                             \
    __syncthreads();                                                           \
  }

  int t = 0;
  for (; t + 1 < tmin; ){   // no-freeze main loop (t and t+1 both < all ln)
    GRU_STEP(0, aen, aec, pra, pza, dea, prb, pzb, deb, 0, 1); ++t;
    GRU_STEP(0, aec, aen, prb, pzb, deb, pra, pza, dea, 1, 0); ++t;
  }
  for (; t + 1 < tmax; ){   // tail pairs with freeze (parity preserved)
    GRU_STEP(1, aen, aec, pra, pza, dea, prb, pzb, deb, 0, 1); ++t;
    GRU_STEP(1, aec, aen, prb, pzb, deb, pra, pza, dea, 1, 0); ++t;
  }
  if (t < tmax){
    GRU_STEP(1, aen, aec, pra, pza, dea, prb, pzb, deb, 0, 1); ++t;
  }
  #undef GRU_STEP

  #pragma unroll
  for (int r = 0; r < 4; ++r)
    out[(size_t)sq[r] * HS + uu] = h[r];
}

extern "C" void kernel_launch(void* const* d_in, const int* in_sizes, int n_in,
                              void* d_out, int out_size, void* d_ws, size_t ws_size,
                              hipStream_t stream){
  const int*   x   = (const int*)  d_in[0];
  const float* emb = (const float*)d_in[1];
  const float* wih = (const float*)d_in[2];
  const float* whh = (const float*)d_in[3];
  const float* bih = (const float*)d_in[4];
  const float* bhh = (const float*)d_in[5];
  float* out = (float*)d_out;

  char* ws = (char*)d_ws;
  size_t off = 0;
  _Float16* ef  = (_Float16*)(ws + off);  off += (size_t)VOCAB * ES * sizeof(_Float16);
  _Float16* wpk = (_Float16*)(ws + off);  off += (size_t)24 * 64 * 8 * sizeof(_Float16);
  _Float16* wpe = (_Float16*)(ws + off);  off += (size_t)12 * 64 * 8 * sizeof(_Float16);
  off = (off + 255) & ~(size_t)255;
  int* len  = (int*)(ws + off);           off += (size_t)N_SEQ * sizeof(int);
  int* perm = (int*)(ws + off);           off += (size_t)N_SEQ * sizeof(int);
  int* hist = (int*)(ws + off);           off += 513 * sizeof(int);
  int* gcnt = (int*)(ws + off);           off += 513 * sizeof(int);

  hipMemsetAsync(hist, 0, 2 * 513 * sizeof(int), stream);   // hist + gcnt
  k_prep   <<<NLB + NEB + 9, 256,  0, stream>>>(x, emb, whh, wih, len, hist, ef, wpk, wpe);
  k_scatter<<<N_SEQ / 1024, 1024,  0, stream>>>(hist, len, gcnt, perm);
  k_gru    <<<N_SEQ / 16,    256,  0, stream>>>(x, ef, wpk, wpe, bih, bhh, perm, len, out);
}